// Round 9
// baseline (971.362 us; speedup 1.0000x reference)
//
#include <hip/hip_runtime.h>
#include <hip/hip_bf16.h>

#define EPS 1e-5f
#define SCAN_BLOCKS 256

typedef __attribute__((ext_vector_type(8))) short bf16x8;
typedef __attribute__((ext_vector_type(4))) float f32x4;

__device__ inline float bf2f(unsigned short u) {
    union { unsigned int i; float f; } v;
    v.i = ((unsigned int)u) << 16;
    return v.f;
}

__device__ inline unsigned short f2bf(float f) {
    union { float f; unsigned int i; } v;
    v.f = f;
    unsigned int x = v.i;
    unsigned int rounded = x + 0x7FFF + ((x >> 16) & 1);   // RNE
    return (unsigned short)(rounded >> 16);
}

// ---------------------------------------------------------------- degree/CSR

__global__ void count_kernel(const int* __restrict__ dst, int* __restrict__ counts, int e) {
    int i = blockIdx.x * blockDim.x + threadIdx.x;
    if (i < e) atomicAdd(&counts[dst[i]], 1);
}

__global__ __launch_bounds__(256) void scan_partial_kernel(const int* __restrict__ counts,
                                                           int* __restrict__ partials, int n) {
    __shared__ int sh[256];
    int chunk = (n + gridDim.x - 1) / gridDim.x;
    int lo = blockIdx.x * chunk;
    int hi = lo + chunk; if (hi > n) hi = n;
    int s = 0;
    for (int i = lo + threadIdx.x; i < hi; i += 256) s += counts[i];
    sh[threadIdx.x] = s;
    __syncthreads();
    for (int d = 128; d; d >>= 1) {
        if (threadIdx.x < d) sh[threadIdx.x] += sh[threadIdx.x + d];
        __syncthreads();
    }
    if (threadIdx.x == 0) partials[blockIdx.x] = sh[0];
}

__global__ __launch_bounds__(256) void scan_level2_kernel(int* __restrict__ partials) {
    __shared__ int sh[256];
    int t = threadIdx.x;
    sh[t] = partials[t];
    __syncthreads();
    for (int d = 1; d < 256; d <<= 1) {
        int v = (t >= d) ? sh[t - d] : 0;
        __syncthreads();
        sh[t] += v;
        __syncthreads();
    }
    partials[t] = (t == 0) ? 0 : sh[t - 1];
}

__global__ __launch_bounds__(256) void scan_write_kernel(const int* __restrict__ counts,
                                                         const int* __restrict__ partials,
                                                         int* __restrict__ offs,
                                                         float* __restrict__ dinv, int n) {
    __shared__ int sh[256];
    int t = threadIdx.x;
    int chunk = (n + gridDim.x - 1) / gridDim.x;
    int lo = blockIdx.x * chunk;
    int hi = lo + chunk; if (hi > n) hi = n;
    int per = (chunk + 255) / 256;
    int tlo = lo + t * per;
    int thi = tlo + per; if (thi > hi) thi = hi;
    int s = 0;
    for (int i = tlo; i < thi; ++i) s += counts[i];
    sh[t] = s;
    __syncthreads();
    for (int d = 1; d < 256; d <<= 1) {
        int v = (t >= d) ? sh[t - d] : 0;
        __syncthreads();
        sh[t] += v;
        __syncthreads();
    }
    int run = partials[blockIdx.x] + ((t == 0) ? 0 : sh[t - 1]);
    for (int i = tlo; i < thi; ++i) {
        offs[i] = run;
        run += counts[i];
        dinv[i] = rsqrtf((float)(counts[i] + 1));  // +1 self loop
    }
    if (tlo < n && thi == n) offs[n] = run;
}

// csr[pos] = (src, bitcast(norm))
__global__ void scatter_kernel(const int* __restrict__ src, const int* __restrict__ dst,
                               const int* __restrict__ offs, int* __restrict__ fill,
                               const float* __restrict__ dinv,
                               int2* __restrict__ csr, int e) {
    int i = blockIdx.x * blockDim.x + threadIdx.x;
    if (i >= e) return;
    int s = src[i], d = dst[i];
    int pos = offs[d] + atomicAdd(&fill[d], 1);
    float w = dinv[s] * dinv[d];
    csr[pos] = make_int2(s, __float_as_int(w));
}

// ---------------------------------------------------------------- weight prep
__global__ void prep_weights_kernel(const float* __restrict__ W1, const float* __restrict__ W2,
                                    const float* __restrict__ W3,
                                    unsigned short* __restrict__ WT1,
                                    unsigned short* __restrict__ WT2,
                                    unsigned short* __restrict__ WT3) {
    int i = blockIdx.x * blockDim.x + threadIdx.x;
    if (i < 16384) {
        int col = i >> 7, k = i & 127;
        WT1[i] = f2bf(W1[k * 128 + col]);
    } else if (i < 32768) {
        int j = i - 16384;
        int col = j >> 7, k = j & 127;
        WT2[j] = f2bf(W2[k * 128 + col]);
    } else if (i < 32768 + 6144) {
        int j = i - 32768;
        int col = j >> 7, k = j & 127;
        WT3[j] = (col < 40) ? f2bf(W3[k * 40 + col]) : 0;
    }
}

// ---------------------------------------------------------------- MFMA GEMM 128x128
// C[n,128](bf16) = act(A[n,128]) @ W; W given as WT[col][k] bf16.
// MODE 0: A f32, no BN (layer 1). MODE 1: A bf16, BN(stats,gamma,beta)+ReLU in staging.
template<int MODE>
__global__ __launch_bounds__(256) void gemm128_mfma_kernel(
    const void* __restrict__ Aptr, const unsigned short* __restrict__ WT,
    const float* __restrict__ stats, const float* __restrict__ gamma,
    const float* __restrict__ beta, float invn,
    unsigned short* __restrict__ C, int n) {
    __shared__ unsigned short lW[128 * 128];  // 32 KB [col][k] swizzled
    __shared__ unsigned short lA[64 * 128];   // 16 KB [row][k] swizzled
    __shared__ float scs[128], shs[128];
    int tid = threadIdx.x;
    if (MODE == 1) {
        if (tid < 128) {
            float mu = stats[tid] * invn;
            float var = stats[128 + tid] * invn - mu * mu;
            float sc = gamma[tid] * rsqrtf(var + EPS);
            scs[tid] = sc;
            shs[tid] = beta[tid] - mu * sc;
        }
        __syncthreads();
    }
    const uint4* wsrc = (const uint4*)WT;
#pragma unroll
    for (int it = 0; it < 8; ++it) {
        int idx = tid + it * 256;
        int byte = idx << 4;
        int dst = byte ^ (((byte >> 8) & 7) << 4);
        *(uint4*)((char*)lW + dst) = wsrc[idx];
    }
    int row0 = blockIdx.x * 64;
#pragma unroll
    for (int it = 0; it < 4; ++it) {
        int idx = tid + it * 256;   // 16-B chunk (8 bf16) in lA
        int r = idx >> 4;
        int cc = (idx & 15) << 3;
        int gr = row0 + r; if (gr > n - 1) gr = n - 1;   // dup rows masked on write
        union { unsigned short u[8]; uint4 q; } t;
        if (MODE == 0) {
            const float* ap = (const float*)Aptr + (size_t)gr * 128 + cc;
            float4 f0 = *(const float4*)ap;
            float4 f1 = *(const float4*)(ap + 4);
            float v[8] = {f0.x, f0.y, f0.z, f0.w, f1.x, f1.y, f1.z, f1.w};
#pragma unroll
            for (int j = 0; j < 8; ++j) t.u[j] = f2bf(v[j]);
        } else {
            uint4 q = *(const uint4*)((const unsigned short*)Aptr + (size_t)gr * 128 + cc);
            unsigned int w[4] = {q.x, q.y, q.z, q.w};
#pragma unroll
            for (int j = 0; j < 8; ++j) {
                float x = bf2f((unsigned short)(w[j >> 1] >> ((j & 1) * 16)));
                int c = cc + j;
                x = fmaf(x, scs[c], shs[c]);
                x = x > 0.0f ? x : 0.0f;
                t.u[j] = f2bf(x);
            }
        }
        int byte = idx << 4;
        int dst = byte ^ (((byte >> 8) & 7) << 4);
        *(uint4*)((char*)lA + dst) = t.q;
    }
    __syncthreads();

    int lane = tid & 63;
    int mrow0 = (tid >> 6) << 4;            // wave's 16 rows
    int arow = mrow0 + (lane & 15);
    int swz = (lane & 7) << 4;
    int koff = (lane >> 4) << 4;
    const char* pA = (const char*)lA + (arow << 8);
    const char* pB = (const char*)lW + ((lane & 15) << 8);
    f32x4 acc[8];
#pragma unroll
    for (int t8 = 0; t8 < 8; ++t8) acc[t8] = (f32x4){0.f, 0.f, 0.f, 0.f};
#pragma unroll
    for (int kk = 0; kk < 4; ++kk) {
        int kb = (kk << 6) + koff;
        bf16x8 af = *(const bf16x8*)(pA + (kb ^ swz));
#pragma unroll
        for (int t8 = 0; t8 < 8; ++t8) {
            bf16x8 bf = *(const bf16x8*)(pB + (t8 << 12) + (kb ^ swz));
            acc[t8] = __builtin_amdgcn_mfma_f32_16x16x32_bf16(af, bf, acc[t8], 0, 0, 0);
        }
    }
    // C layout: row=(lane>>4)*4+j, col=lane&15 (m89-verified)
    int crow = row0 + mrow0 + ((lane >> 4) << 2);
    int ccol = lane & 15;
    unsigned short* cp = C + (size_t)crow * 128 + ccol;
#pragma unroll
    for (int j = 0; j < 4; ++j) {
        if (crow + j < n) {
#pragma unroll
            for (int t8 = 0; t8 < 8; ++t8)
                cp[(size_t)j * 128 + t8 * 16] = f2bf(acc[t8][j]);
        }
    }
}

// ---------------------------------------------------------------- MFMA GEMM 128x40 + log_softmax
__global__ __launch_bounds__(256) void gemm40_lsm_mfma_kernel(
    const unsigned short* __restrict__ A, const unsigned short* __restrict__ WT,
    const float* __restrict__ b3, float* __restrict__ out, int n) {
    __shared__ unsigned short lW[48 * 128];   // 12 KB
    __shared__ unsigned short lA[64 * 128];   // 16 KB
    __shared__ float sRow[64 * 49];
    __shared__ float sD[64];
    __shared__ float sB[48];
    int tid = threadIdx.x;
    if (tid < 48) sB[tid] = (tid < 40) ? b3[tid] : 0.0f;
    const uint4* wsrc = (const uint4*)WT;
#pragma unroll
    for (int it = 0; it < 3; ++it) {
        int idx = tid + it * 256;
        int byte = idx << 4;
        int dst = byte ^ (((byte >> 8) & 7) << 4);
        *(uint4*)((char*)lW + dst) = wsrc[idx];
    }
    int row0 = blockIdx.x * 64;
#pragma unroll
    for (int it = 0; it < 4; ++it) {
        int idx = tid + it * 256;
        int r = idx >> 4;
        int cc = (idx & 15) << 3;
        int gr = row0 + r; if (gr > n - 1) gr = n - 1;
        uint4 q = *(const uint4*)(A + (size_t)gr * 128 + cc);
        int byte = idx << 4;
        int dst = byte ^ (((byte >> 8) & 7) << 4);
        *(uint4*)((char*)lA + dst) = q;
    }
    __syncthreads();

    int lane = tid & 63;
    int mrow0 = (tid >> 6) << 4;
    int arow = mrow0 + (lane & 15);
    int swz = (lane & 7) << 4;
    int koff = (lane >> 4) << 4;
    const char* pA = (const char*)lA + (arow << 8);
    const char* pB = (const char*)lW + ((lane & 15) << 8);
    f32x4 acc[3];
#pragma unroll
    for (int t8 = 0; t8 < 3; ++t8) acc[t8] = (f32x4){0.f, 0.f, 0.f, 0.f};
#pragma unroll
    for (int kk = 0; kk < 4; ++kk) {
        int kb = (kk << 6) + koff;
        bf16x8 af = *(const bf16x8*)(pA + (kb ^ swz));
#pragma unroll
        for (int t8 = 0; t8 < 3; ++t8) {
            bf16x8 bf = *(const bf16x8*)(pB + (t8 << 12) + (kb ^ swz));
            acc[t8] = __builtin_amdgcn_mfma_f32_16x16x32_bf16(af, bf, acc[t8], 0, 0, 0);
        }
    }
    int lrow = mrow0 + ((lane >> 4) << 2);
    int ccol = lane & 15;
#pragma unroll
    for (int t8 = 0; t8 < 3; ++t8)
#pragma unroll
        for (int j = 0; j < 4; ++j)
            sRow[(lrow + j) * 49 + t8 * 16 + ccol] = acc[t8][j] + sB[t8 * 16 + ccol];
    __syncthreads();
    if (tid < 64) {
        float m = -1e30f;
        for (int c = 0; c < 40; ++c) m = fmaxf(m, sRow[tid * 49 + c]);
        float l = 0.0f;
        for (int c = 0; c < 40; ++c) l += expf(sRow[tid * 49 + c] - m);
        sD[tid] = m + logf(l);
    }
    __syncthreads();
    for (int i = tid; i < 64 * 40; i += 256) {
        int r = i / 40;
        int c = i - r * 40;
        int gr = row0 + r;
        if (gr < n) out[(size_t)gr * 40 + c] = sRow[r * 49 + c] - sD[r];
    }
}

// ---------------------------------------------------------------- aggregation

// out[node,:](bf16) = dinv^2*act(H[node,:]) + sum_e w_e*act(H[col_e,:]), H bf16
// one 64-lane wave per node (grid-strided), 4-edge unroll.
// MODE 0: plain; accumulate per-col (sum, sumsq) in registers, flush via 4 atomics/wave.
// MODE 1: act = relu(bn(.)) fused per gathered element (layer-3), no stats.
template<int MODE>
__global__ __launch_bounds__(256) void aggregate128_kernel(
    const unsigned short* __restrict__ H, const int* __restrict__ offs,
    const int2* __restrict__ csr, const float* __restrict__ dinv,
    const float* __restrict__ stats, const float* __restrict__ gamma,
    const float* __restrict__ beta, float invn,
    unsigned short* __restrict__ out, float* __restrict__ statsOut, int n) {
    int wid = (blockIdx.x * blockDim.x + threadIdx.x) >> 6;
    int nw = (gridDim.x * blockDim.x) >> 6;
    int lane = threadIdx.x & 63;
    int c0 = lane * 2;
    float sc0 = 1.0f, sh0 = 0.0f, sc1 = 1.0f, sh1 = 0.0f;
    if (MODE == 1) {
        float mu0 = stats[c0] * invn;
        float var0 = stats[128 + c0] * invn - mu0 * mu0;
        sc0 = gamma[c0] * rsqrtf(var0 + EPS);
        sh0 = beta[c0] - mu0 * sc0;
        float mu1 = stats[c0 + 1] * invn;
        float var1 = stats[128 + c0 + 1] * invn - mu1 * mu1;
        sc1 = gamma[c0 + 1] * rsqrtf(var1 + EPS);
        sh1 = beta[c0 + 1] - mu1 * sc1;
    }
    auto loadf = [&](int row) -> float2 {
        unsigned int hv = *(const unsigned int*)(H + (size_t)row * 128 + c0);
        float x0 = bf2f((unsigned short)hv);
        float x1 = bf2f((unsigned short)(hv >> 16));
        if (MODE == 1) {
            x0 = fmaf(x0, sc0, sh0); x0 = x0 > 0.0f ? x0 : 0.0f;
            x1 = fmaf(x1, sc1, sh1); x1 = x1 > 0.0f ? x1 : 0.0f;
        }
        return make_float2(x0, x1);
    };
    float s0 = 0.0f, s1 = 0.0f, q0 = 0.0f, q1 = 0.0f;
    for (int node = wid; node < n; node += nw) {
        float di = dinv[node];
        float dd = di * di;
        float2 self = loadf(node);
        float2 a0 = make_float2(self.x * dd, self.y * dd);
        float2 a1 = make_float2(0.f, 0.f), a2 = make_float2(0.f, 0.f),
               a3 = make_float2(0.f, 0.f);
        int e = offs[node], e1 = offs[node + 1];
        for (; e + 4 <= e1; e += 4) {
            int2 e0v = csr[e], e1v = csr[e + 1], e2v = csr[e + 2], e3v = csr[e + 3];
            float2 h0 = loadf(e0v.x);
            float2 h1 = loadf(e1v.x);
            float2 h2 = loadf(e2v.x);
            float2 h3 = loadf(e3v.x);
            float w0 = __int_as_float(e0v.y), w1 = __int_as_float(e1v.y);
            float w2 = __int_as_float(e2v.y), w3 = __int_as_float(e3v.y);
            a0.x = fmaf(h0.x, w0, a0.x); a0.y = fmaf(h0.y, w0, a0.y);
            a1.x = fmaf(h1.x, w1, a1.x); a1.y = fmaf(h1.y, w1, a1.y);
            a2.x = fmaf(h2.x, w2, a2.x); a2.y = fmaf(h2.y, w2, a2.y);
            a3.x = fmaf(h3.x, w3, a3.x); a3.y = fmaf(h3.y, w3, a3.y);
        }
        for (; e < e1; ++e) {
            int2 qv = csr[e];
            float2 h = loadf(qv.x);
            float w = __int_as_float(qv.y);
            a0.x = fmaf(h.x, w, a0.x); a0.y = fmaf(h.y, w, a0.y);
        }
        float rx = (a0.x + a1.x) + (a2.x + a3.x);
        float ry = (a0.y + a1.y) + (a2.y + a3.y);
        if (MODE == 0) {
            s0 += rx; s1 += ry;
            q0 = fmaf(rx, rx, q0); q1 = fmaf(ry, ry, q1);
        }
        unsigned int pack = (unsigned int)f2bf(rx) | ((unsigned int)f2bf(ry) << 16);
        *(unsigned int*)(out + (size_t)node * 128 + c0) = pack;
    }
    if (MODE == 0) {
        atomicAdd(&statsOut[c0], s0);
        atomicAdd(&statsOut[c0 + 1], s1);
        atomicAdd(&statsOut[128 + c0], q0);
        atomicAdd(&statsOut[128 + c0 + 1], q1);
    }
}

// ---------------------------------------------------------------- launch

extern "C" void kernel_launch(void* const* d_in, const int* in_sizes, int n_in,
                              void* d_out, int out_size, void* d_ws, size_t ws_size,
                              hipStream_t stream) {
    const float* x   = (const float*)d_in[0];
    const int*   ei  = (const int*)d_in[1];
    const float* W1  = (const float*)d_in[2];
    const float* g1  = (const float*)d_in[4];
    const float* bt1 = (const float*)d_in[5];
    const float* W2  = (const float*)d_in[6];
    const float* g2  = (const float*)d_in[8];
    const float* bt2 = (const float*)d_in[9];
    const float* W3  = (const float*)d_in[10];
    const float* b3  = (const float*)d_in[11];

    int n = in_sizes[0] / 128;
    int e = in_sizes[1] / 2;
    const int* src = ei;
    const int* dst = ei + e;

    char* p = (char*)d_ws;
    auto alloc = [&](size_t bytes) -> char* {
        char* q = p;
        p += (bytes + 255) & ~(size_t)255;
        return q;
    };
    int*            counts   = (int*)alloc((size_t)n * 4);
    int*            offs     = (int*)alloc((size_t)(n + 1) * 4);
    int*            fill     = (int*)alloc((size_t)n * 4);
    float*          dinv     = (float*)alloc((size_t)n * 4);
    int*            partials = (int*)alloc(SCAN_BLOCKS * 4);
    int2*           csr      = (int2*)alloc((size_t)e * 8);
    float*          stats    = (float*)alloc(512 * 4);
    unsigned short* WT1      = (unsigned short*)alloc(16384 * 2);
    unsigned short* WT2      = (unsigned short*)alloc(16384 * 2);
    unsigned short* WT3      = (unsigned short*)alloc(6144 * 2);
    unsigned short* Hb       = (unsigned short*)alloc((size_t)n * 128 * 2);
    unsigned short* Ab       = (unsigned short*)alloc((size_t)n * 128 * 2);
    unsigned short* Ab2      = (unsigned short*)alloc((size_t)n * 128 * 2);
    unsigned short* Hb2      = (unsigned short*)alloc((size_t)n * 128 * 2);

    hipMemsetAsync(counts, 0, (size_t)n * 4, stream);
    hipMemsetAsync(fill, 0, (size_t)n * 4, stream);
    hipMemsetAsync(stats, 0, 512 * 4, stream);

    const int tb = 256;
    float invn = 1.0f / n;
    prep_weights_kernel<<<(38912 + tb - 1) / tb, tb, 0, stream>>>(W1, W2, W3, WT1, WT2, WT3);
    count_kernel<<<(e + tb - 1) / tb, tb, 0, stream>>>(dst, counts, e);
    scan_partial_kernel<<<SCAN_BLOCKS, tb, 0, stream>>>(counts, partials, n);
    scan_level2_kernel<<<1, tb, 0, stream>>>(partials);
    scan_write_kernel<<<SCAN_BLOCKS, tb, 0, stream>>>(counts, partials, offs, dinv, n);
    scatter_kernel<<<(e + tb - 1) / tb, tb, 0, stream>>>(src, dst, offs, fill, dinv, csr, e);

    int gblocks = (n + 63) / 64;
    int ablocks = 2048;   // grid-stride: 8192 waves over n nodes

    // layer 1 (b1/b2 dropped: BN cancels constant shift); stats1 fused into aggregate
    gemm128_mfma_kernel<0><<<gblocks, tb, 0, stream>>>(x, WT1, nullptr, nullptr, nullptr,
                                                       0.0f, Hb, n);
    aggregate128_kernel<0><<<ablocks, tb, 0, stream>>>(Hb, offs, csr, dinv, nullptr, nullptr,
                                                       nullptr, 0.0f, Ab, stats, n);
    // layer 2: BN1+ReLU fused into gemm A-staging; stats2 fused into aggregate
    gemm128_mfma_kernel<1><<<gblocks, tb, 0, stream>>>(Ab, WT2, stats, g1, bt1, invn, Hb, n);
    aggregate128_kernel<0><<<ablocks, tb, 0, stream>>>(Hb, offs, csr, dinv, nullptr, nullptr,
                                                       nullptr, 0.0f, Ab2, stats + 256, n);
    // layer 3: BN2+ReLU fused into aggregation gather; then GEMM + fused log_softmax
    aggregate128_kernel<1><<<ablocks, tb, 0, stream>>>(Ab2, offs, csr, dinv, stats + 256,
                                                       g2, bt2, invn, Hb2, nullptr, n);
    gemm40_lsm_mfma_kernel<<<gblocks, tb, 0, stream>>>(Hb2, WT3, b3, (float*)d_out, n);
}

// Round 10
// 269.145 us; speedup vs baseline: 3.6091x; 3.6091x over previous
//
#include <hip/hip_runtime.h>
#include <hip/hip_bf16.h>

#define EPS 1e-5f
#define SCAN_BLOCKS 256

typedef __attribute__((ext_vector_type(8))) short bf16x8;
typedef __attribute__((ext_vector_type(4))) float f32x4;

__device__ inline float bf2f(unsigned short u) {
    union { unsigned int i; float f; } v;
    v.i = ((unsigned int)u) << 16;
    return v.f;
}

__device__ inline unsigned short f2bf(float f) {
    union { float f; unsigned int i; } v;
    v.f = f;
    unsigned int x = v.i;
    unsigned int rounded = x + 0x7FFF + ((x >> 16) & 1);   // RNE
    return (unsigned short)(rounded >> 16);
}

// ---------------------------------------------------------------- degree/CSR

__global__ void count_kernel(const int* __restrict__ dst, int* __restrict__ counts, int e) {
    int i = blockIdx.x * blockDim.x + threadIdx.x;
    if (i < e) atomicAdd(&counts[dst[i]], 1);
}

__global__ __launch_bounds__(256) void scan_partial_kernel(const int* __restrict__ counts,
                                                           int* __restrict__ partials, int n) {
    __shared__ int sh[256];
    int chunk = (n + gridDim.x - 1) / gridDim.x;
    int lo = blockIdx.x * chunk;
    int hi = lo + chunk; if (hi > n) hi = n;
    int s = 0;
    for (int i = lo + threadIdx.x; i < hi; i += 256) s += counts[i];
    sh[threadIdx.x] = s;
    __syncthreads();
    for (int d = 128; d; d >>= 1) {
        if (threadIdx.x < d) sh[threadIdx.x] += sh[threadIdx.x + d];
        __syncthreads();
    }
    if (threadIdx.x == 0) partials[blockIdx.x] = sh[0];
}

__global__ __launch_bounds__(256) void scan_level2_kernel(int* __restrict__ partials) {
    __shared__ int sh[256];
    int t = threadIdx.x;
    sh[t] = partials[t];
    __syncthreads();
    for (int d = 1; d < 256; d <<= 1) {
        int v = (t >= d) ? sh[t - d] : 0;
        __syncthreads();
        sh[t] += v;
        __syncthreads();
    }
    partials[t] = (t == 0) ? 0 : sh[t - 1];
}

__global__ __launch_bounds__(256) void scan_write_kernel(const int* __restrict__ counts,
                                                         const int* __restrict__ partials,
                                                         int* __restrict__ offs,
                                                         float* __restrict__ dinv, int n) {
    __shared__ int sh[256];
    int t = threadIdx.x;
    int chunk = (n + gridDim.x - 1) / gridDim.x;
    int lo = blockIdx.x * chunk;
    int hi = lo + chunk; if (hi > n) hi = n;
    int per = (chunk + 255) / 256;
    int tlo = lo + t * per;
    int thi = tlo + per; if (thi > hi) thi = hi;
    int s = 0;
    for (int i = tlo; i < thi; ++i) s += counts[i];
    sh[t] = s;
    __syncthreads();
    for (int d = 1; d < 256; d <<= 1) {
        int v = (t >= d) ? sh[t - d] : 0;
        __syncthreads();
        sh[t] += v;
        __syncthreads();
    }
    int run = partials[blockIdx.x] + ((t == 0) ? 0 : sh[t - 1]);
    for (int i = tlo; i < thi; ++i) {
        offs[i] = run;
        run += counts[i];
        dinv[i] = rsqrtf((float)(counts[i] + 1));  // +1 self loop
    }
    if (tlo < n && thi == n) offs[n] = run;
}

// csr[pos] = (src, bitcast(norm))
__global__ void scatter_kernel(const int* __restrict__ src, const int* __restrict__ dst,
                               const int* __restrict__ offs, int* __restrict__ fill,
                               const float* __restrict__ dinv,
                               int2* __restrict__ csr, int e) {
    int i = blockIdx.x * blockDim.x + threadIdx.x;
    if (i >= e) return;
    int s = src[i], d = dst[i];
    int pos = offs[d] + atomicAdd(&fill[d], 1);
    float w = dinv[s] * dinv[d];
    csr[pos] = make_int2(s, __float_as_int(w));
}

// ---------------------------------------------------------------- weight prep
__global__ void prep_weights_kernel(const float* __restrict__ W1, const float* __restrict__ W2,
                                    const float* __restrict__ W3,
                                    unsigned short* __restrict__ WT1,
                                    unsigned short* __restrict__ WT2,
                                    unsigned short* __restrict__ WT3) {
    int i = blockIdx.x * blockDim.x + threadIdx.x;
    if (i < 16384) {
        int col = i >> 7, k = i & 127;
        WT1[i] = f2bf(W1[k * 128 + col]);
    } else if (i < 32768) {
        int j = i - 16384;
        int col = j >> 7, k = j & 127;
        WT2[j] = f2bf(W2[k * 128 + col]);
    } else if (i < 32768 + 6144) {
        int j = i - 32768;
        int col = j >> 7, k = j & 127;
        WT3[j] = (col < 40) ? f2bf(W3[k * 40 + col]) : 0;
    }
}

// ---------------------------------------------------------------- MFMA GEMM 128x128
// C[n,128](bf16) = act(A[n,128]) @ W; W given as WT[col][k] bf16.
// MODE 0: A f32, no BN (layer 1). MODE 1: A bf16, BN(stats,gamma,beta)+ReLU in staging.
template<int MODE>
__global__ __launch_bounds__(256) void gemm128_mfma_kernel(
    const void* __restrict__ Aptr, const unsigned short* __restrict__ WT,
    const float* __restrict__ stats, const float* __restrict__ gamma,
    const float* __restrict__ beta, float invn,
    unsigned short* __restrict__ C, int n) {
    __shared__ unsigned short lW[128 * 128];  // 32 KB [col][k] swizzled
    __shared__ unsigned short lA[64 * 128];   // 16 KB [row][k] swizzled
    __shared__ float scs[128], shs[128];
    int tid = threadIdx.x;
    if (MODE == 1) {
        if (tid < 128) {
            float mu = stats[tid] * invn;
            float var = stats[128 + tid] * invn - mu * mu;
            float sc = gamma[tid] * rsqrtf(var + EPS);
            scs[tid] = sc;
            shs[tid] = beta[tid] - mu * sc;
        }
        __syncthreads();
    }
    const uint4* wsrc = (const uint4*)WT;
#pragma unroll
    for (int it = 0; it < 8; ++it) {
        int idx = tid + it * 256;
        int byte = idx << 4;
        int dst = byte ^ (((byte >> 8) & 7) << 4);
        *(uint4*)((char*)lW + dst) = wsrc[idx];
    }
    int row0 = blockIdx.x * 64;
#pragma unroll
    for (int it = 0; it < 4; ++it) {
        int idx = tid + it * 256;   // 16-B chunk (8 bf16) in lA
        int r = idx >> 4;
        int cc = (idx & 15) << 3;
        int gr = row0 + r; if (gr > n - 1) gr = n - 1;   // dup rows masked on write
        union { unsigned short u[8]; uint4 q; } t;
        if (MODE == 0) {
            const float* ap = (const float*)Aptr + (size_t)gr * 128 + cc;
            float4 f0 = *(const float4*)ap;
            float4 f1 = *(const float4*)(ap + 4);
            float v[8] = {f0.x, f0.y, f0.z, f0.w, f1.x, f1.y, f1.z, f1.w};
#pragma unroll
            for (int j = 0; j < 8; ++j) t.u[j] = f2bf(v[j]);
        } else {
            uint4 q = *(const uint4*)((const unsigned short*)Aptr + (size_t)gr * 128 + cc);
            unsigned int w[4] = {q.x, q.y, q.z, q.w};
#pragma unroll
            for (int j = 0; j < 8; ++j) {
                float x = bf2f((unsigned short)(w[j >> 1] >> ((j & 1) * 16)));
                int c = cc + j;
                x = fmaf(x, scs[c], shs[c]);
                x = x > 0.0f ? x : 0.0f;
                t.u[j] = f2bf(x);
            }
        }
        int byte = idx << 4;
        int dst = byte ^ (((byte >> 8) & 7) << 4);
        *(uint4*)((char*)lA + dst) = t.q;
    }
    __syncthreads();

    int lane = tid & 63;
    int mrow0 = (tid >> 6) << 4;            // wave's 16 rows
    int arow = mrow0 + (lane & 15);
    int swz = (lane & 7) << 4;
    int koff = (lane >> 4) << 4;
    const char* pA = (const char*)lA + (arow << 8);
    const char* pB = (const char*)lW + ((lane & 15) << 8);
    f32x4 acc[8];
#pragma unroll
    for (int t8 = 0; t8 < 8; ++t8) acc[t8] = (f32x4){0.f, 0.f, 0.f, 0.f};
#pragma unroll
    for (int kk = 0; kk < 4; ++kk) {
        int kb = (kk << 6) + koff;
        bf16x8 af = *(const bf16x8*)(pA + (kb ^ swz));
#pragma unroll
        for (int t8 = 0; t8 < 8; ++t8) {
            bf16x8 bf = *(const bf16x8*)(pB + (t8 << 12) + (kb ^ swz));
            acc[t8] = __builtin_amdgcn_mfma_f32_16x16x32_bf16(af, bf, acc[t8], 0, 0, 0);
        }
    }
    // C layout: row=(lane>>4)*4+j, col=lane&15 (m89-verified)
    int crow = row0 + mrow0 + ((lane >> 4) << 2);
    int ccol = lane & 15;
    unsigned short* cp = C + (size_t)crow * 128 + ccol;
#pragma unroll
    for (int j = 0; j < 4; ++j) {
        if (crow + j < n) {
#pragma unroll
            for (int t8 = 0; t8 < 8; ++t8)
                cp[(size_t)j * 128 + t8 * 16] = f2bf(acc[t8][j]);
        }
    }
}

// ---------------------------------------------------------------- MFMA GEMM 128x40 + log_softmax
__global__ __launch_bounds__(256) void gemm40_lsm_mfma_kernel(
    const unsigned short* __restrict__ A, const unsigned short* __restrict__ WT,
    const float* __restrict__ b3, float* __restrict__ out, int n) {
    __shared__ unsigned short lW[48 * 128];   // 12 KB
    __shared__ unsigned short lA[64 * 128];   // 16 KB
    __shared__ float sRow[64 * 49];
    __shared__ float sD[64];
    __shared__ float sB[48];
    int tid = threadIdx.x;
    if (tid < 48) sB[tid] = (tid < 40) ? b3[tid] : 0.0f;
    const uint4* wsrc = (const uint4*)WT;
#pragma unroll
    for (int it = 0; it < 3; ++it) {
        int idx = tid + it * 256;
        int byte = idx << 4;
        int dst = byte ^ (((byte >> 8) & 7) << 4);
        *(uint4*)((char*)lW + dst) = wsrc[idx];
    }
    int row0 = blockIdx.x * 64;
#pragma unroll
    for (int it = 0; it < 4; ++it) {
        int idx = tid + it * 256;
        int r = idx >> 4;
        int cc = (idx & 15) << 3;
        int gr = row0 + r; if (gr > n - 1) gr = n - 1;
        uint4 q = *(const uint4*)(A + (size_t)gr * 128 + cc);
        int byte = idx << 4;
        int dst = byte ^ (((byte >> 8) & 7) << 4);
        *(uint4*)((char*)lA + dst) = q;
    }
    __syncthreads();

    int lane = tid & 63;
    int mrow0 = (tid >> 6) << 4;
    int arow = mrow0 + (lane & 15);
    int swz = (lane & 7) << 4;
    int koff = (lane >> 4) << 4;
    const char* pA = (const char*)lA + (arow << 8);
    const char* pB = (const char*)lW + ((lane & 15) << 8);
    f32x4 acc[3];
#pragma unroll
    for (int t8 = 0; t8 < 3; ++t8) acc[t8] = (f32x4){0.f, 0.f, 0.f, 0.f};
#pragma unroll
    for (int kk = 0; kk < 4; ++kk) {
        int kb = (kk << 6) + koff;
        bf16x8 af = *(const bf16x8*)(pA + (kb ^ swz));
#pragma unroll
        for (int t8 = 0; t8 < 3; ++t8) {
            bf16x8 bf = *(const bf16x8*)(pB + (t8 << 12) + (kb ^ swz));
            acc[t8] = __builtin_amdgcn_mfma_f32_16x16x32_bf16(af, bf, acc[t8], 0, 0, 0);
        }
    }
    int lrow = mrow0 + ((lane >> 4) << 2);
    int ccol = lane & 15;
#pragma unroll
    for (int t8 = 0; t8 < 3; ++t8)
#pragma unroll
        for (int j = 0; j < 4; ++j)
            sRow[(lrow + j) * 49 + t8 * 16 + ccol] = acc[t8][j] + sB[t8 * 16 + ccol];
    __syncthreads();
    if (tid < 64) {
        float m = -1e30f;
        for (int c = 0; c < 40; ++c) m = fmaxf(m, sRow[tid * 49 + c]);
        float l = 0.0f;
        for (int c = 0; c < 40; ++c) l += expf(sRow[tid * 49 + c] - m);
        sD[tid] = m + logf(l);
    }
    __syncthreads();
    for (int i = tid; i < 64 * 40; i += 256) {
        int r = i / 40;
        int c = i - r * 40;
        int gr = row0 + r;
        if (gr < n) out[(size_t)gr * 40 + c] = sRow[r * 49 + c] - sD[r];
    }
}

// ---------------------------------------------------------------- aggregation

// Two consecutive nodes per wave, concatenated edge loop (one continuous 4-deep
// load pipeline across the node boundary; branchless A/B routing via weight select).
// out[node,:](bf16) = dinv^2*act(H[node,:]) + sum_e w_e*act(H[col_e,:]), H bf16.
// BN: act = relu(bn(.)) fused per gathered element (layer-3).
template<bool BN>
__global__ __launch_bounds__(256) void aggregate128_kernel(
    const unsigned short* __restrict__ H, const int* __restrict__ offs,
    const int2* __restrict__ csr, const float* __restrict__ dinv,
    const float* __restrict__ stats, const float* __restrict__ gamma,
    const float* __restrict__ beta, float invn,
    unsigned short* __restrict__ out, int n) {
    int w = (blockIdx.x * blockDim.x + threadIdx.x) >> 6;
    int n0 = w * 2;
    if (n0 >= n) return;
    int n1 = n0 + 1;
    bool has1 = n1 < n;
    int lane = threadIdx.x & 63;
    int c0 = lane * 2;
    float sc0 = 1.0f, sh0 = 0.0f, sc1 = 1.0f, sh1 = 0.0f;
    if (BN) {
        float mu0 = stats[c0] * invn;
        float var0 = stats[128 + c0] * invn - mu0 * mu0;
        sc0 = gamma[c0] * rsqrtf(var0 + EPS);
        sh0 = beta[c0] - mu0 * sc0;
        float mu1 = stats[c0 + 1] * invn;
        float var1 = stats[128 + c0 + 1] * invn - mu1 * mu1;
        sc1 = gamma[c0 + 1] * rsqrtf(var1 + EPS);
        sh1 = beta[c0 + 1] - mu1 * sc1;
    }
    auto loadf = [&](int row) -> float2 {
        unsigned int hv = *(const unsigned int*)(H + (size_t)row * 128 + c0);
        float x0 = bf2f((unsigned short)hv);
        float x1 = bf2f((unsigned short)(hv >> 16));
        if (BN) {
            x0 = fmaf(x0, sc0, sh0); x0 = x0 > 0.0f ? x0 : 0.0f;
            x1 = fmaf(x1, sc1, sh1); x1 = x1 > 0.0f ? x1 : 0.0f;
        }
        return make_float2(x0, x1);
    };
    int e0 = offs[n0];
    int b  = offs[n1];                 // boundary (offs[n] valid: == e total)
    int eE = has1 ? offs[n1 + 1] : b;
    // self terms
    float di = dinv[n0];
    float2 sA = loadf(n0);
    float2 A = make_float2(sA.x * di * di, sA.y * di * di);
    float2 B = make_float2(0.f, 0.f);
    if (has1) {
        float dj = dinv[n1];
        float2 sB2 = loadf(n1);
        B.x = sB2.x * dj * dj; B.y = sB2.y * dj * dj;
    }
    float2 a0 = make_float2(0.f, 0.f), a1 = a0, a2 = a0, a3 = a0;
    float2 b0 = a0, b1 = a0, b2 = a0, b3 = a0;
    int e = e0;
    for (; e + 4 <= eE; e += 4) {
        int2 q0 = csr[e], q1 = csr[e + 1], q2 = csr[e + 2], q3 = csr[e + 3];
        float2 h0 = loadf(q0.x);
        float2 h1 = loadf(q1.x);
        float2 h2 = loadf(q2.x);
        float2 h3 = loadf(q3.x);
        float w0 = __int_as_float(q0.y), w1 = __int_as_float(q1.y);
        float w2 = __int_as_float(q2.y), w3 = __int_as_float(q3.y);
        float wa0 = (e + 0 < b) ? w0 : 0.f, wb0 = (e + 0 < b) ? 0.f : w0;
        float wa1 = (e + 1 < b) ? w1 : 0.f, wb1 = (e + 1 < b) ? 0.f : w1;
        float wa2 = (e + 2 < b) ? w2 : 0.f, wb2 = (e + 2 < b) ? 0.f : w2;
        float wa3 = (e + 3 < b) ? w3 : 0.f, wb3 = (e + 3 < b) ? 0.f : w3;
        a0.x = fmaf(h0.x, wa0, a0.x); a0.y = fmaf(h0.y, wa0, a0.y);
        b0.x = fmaf(h0.x, wb0, b0.x); b0.y = fmaf(h0.y, wb0, b0.y);
        a1.x = fmaf(h1.x, wa1, a1.x); a1.y = fmaf(h1.y, wa1, a1.y);
        b1.x = fmaf(h1.x, wb1, b1.x); b1.y = fmaf(h1.y, wb1, b1.y);
        a2.x = fmaf(h2.x, wa2, a2.x); a2.y = fmaf(h2.y, wa2, a2.y);
        b2.x = fmaf(h2.x, wb2, b2.x); b2.y = fmaf(h2.y, wb2, b2.y);
        a3.x = fmaf(h3.x, wa3, a3.x); a3.y = fmaf(h3.y, wa3, a3.y);
        b3.x = fmaf(h3.x, wb3, b3.x); b3.y = fmaf(h3.y, wb3, b3.y);
    }
    for (; e < eE; ++e) {
        int2 q = csr[e];
        float2 h = loadf(q.x);
        float wv = __int_as_float(q.y);
        float wa = (e < b) ? wv : 0.f, wb = (e < b) ? 0.f : wv;
        a0.x = fmaf(h.x, wa, a0.x); a0.y = fmaf(h.y, wa, a0.y);
        b0.x = fmaf(h.x, wb, b0.x); b0.y = fmaf(h.y, wb, b0.y);
    }
    A.x += (a0.x + a1.x) + (a2.x + a3.x);
    A.y += (a0.y + a1.y) + (a2.y + a3.y);
    B.x += (b0.x + b1.x) + (b2.x + b3.x);
    B.y += (b0.y + b1.y) + (b2.y + b3.y);
    unsigned int packA = (unsigned int)f2bf(A.x) | ((unsigned int)f2bf(A.y) << 16);
    *(unsigned int*)(out + (size_t)n0 * 128 + c0) = packA;
    if (has1) {
        unsigned int packB = (unsigned int)f2bf(B.x) | ((unsigned int)f2bf(B.y) << 16);
        *(unsigned int*)(out + (size_t)n1 * 128 + c0) = packB;
    }
}

// ---------------------------------------------------------------- batchnorm stats (bf16 in)

__global__ __launch_bounds__(256) void bn_stats_kernel(const unsigned short* __restrict__ X,
                                                       float* __restrict__ stats, int n) {
    int tid = threadIdx.x;
    int c = tid & 127;
    int r0 = blockIdx.x * 2 + (tid >> 7);
    float s = 0.0f, q = 0.0f;
    for (int r = r0; r < n; r += gridDim.x * 2) {
        float v = bf2f(X[(size_t)r * 128 + c]);
        s += v;
        q += v * v;
    }
    __shared__ float sh[256], shq[256];
    sh[tid] = s; shq[tid] = q;
    __syncthreads();
    if (tid < 128) {
        atomicAdd(&stats[c], sh[tid] + sh[tid + 128]);
        atomicAdd(&stats[128 + c], shq[tid] + shq[tid + 128]);
    }
}

// ---------------------------------------------------------------- launch

extern "C" void kernel_launch(void* const* d_in, const int* in_sizes, int n_in,
                              void* d_out, int out_size, void* d_ws, size_t ws_size,
                              hipStream_t stream) {
    const float* x   = (const float*)d_in[0];
    const int*   ei  = (const int*)d_in[1];
    const float* W1  = (const float*)d_in[2];
    const float* g1  = (const float*)d_in[4];
    const float* bt1 = (const float*)d_in[5];
    const float* W2  = (const float*)d_in[6];
    const float* g2  = (const float*)d_in[8];
    const float* bt2 = (const float*)d_in[9];
    const float* W3  = (const float*)d_in[10];
    const float* b3  = (const float*)d_in[11];

    int n = in_sizes[0] / 128;
    int e = in_sizes[1] / 2;
    const int* src = ei;
    const int* dst = ei + e;

    char* p = (char*)d_ws;
    auto alloc = [&](size_t bytes) -> char* {
        char* q = p;
        p += (bytes + 255) & ~(size_t)255;
        return q;
    };
    int*            counts   = (int*)alloc((size_t)n * 4);
    int*            offs     = (int*)alloc((size_t)(n + 1) * 4);
    int*            fill     = (int*)alloc((size_t)n * 4);
    float*          dinv     = (float*)alloc((size_t)n * 4);
    int*            partials = (int*)alloc(SCAN_BLOCKS * 4);
    int2*           csr      = (int2*)alloc((size_t)e * 8);
    float*          stats    = (float*)alloc(512 * 4);
    unsigned short* WT1      = (unsigned short*)alloc(16384 * 2);
    unsigned short* WT2      = (unsigned short*)alloc(16384 * 2);
    unsigned short* WT3      = (unsigned short*)alloc(6144 * 2);
    unsigned short* Hb       = (unsigned short*)alloc((size_t)n * 128 * 2);
    unsigned short* Ab       = (unsigned short*)alloc((size_t)n * 128 * 2);
    unsigned short* Ab2      = (unsigned short*)alloc((size_t)n * 128 * 2);
    unsigned short* Hb2      = (unsigned short*)alloc((size_t)n * 128 * 2);

    hipMemsetAsync(counts, 0, (size_t)n * 4, stream);
    hipMemsetAsync(fill, 0, (size_t)n * 4, stream);
    hipMemsetAsync(stats, 0, 512 * 4, stream);

    const int tb = 256;
    float invn = 1.0f / n;
    prep_weights_kernel<<<(38912 + tb - 1) / tb, tb, 0, stream>>>(W1, W2, W3, WT1, WT2, WT3);
    count_kernel<<<(e + tb - 1) / tb, tb, 0, stream>>>(dst, counts, e);
    scan_partial_kernel<<<SCAN_BLOCKS, tb, 0, stream>>>(counts, partials, n);
    scan_level2_kernel<<<1, tb, 0, stream>>>(partials);
    scan_write_kernel<<<SCAN_BLOCKS, tb, 0, stream>>>(counts, partials, offs, dinv, n);
    scatter_kernel<<<(e + tb - 1) / tb, tb, 0, stream>>>(src, dst, offs, fill, dinv, csr, e);

    int gblocks = (n + 63) / 64;
    int npairs = (n + 1) / 2;
    int ablocks = (npairs + 3) / 4;   // 4 waves/block, 2 nodes/wave

    // layer 1 (b1/b2 dropped: BN cancels constant shift)
    gemm128_mfma_kernel<0><<<gblocks, tb, 0, stream>>>(x, WT1, nullptr, nullptr, nullptr,
                                                       0.0f, Hb, n);
    aggregate128_kernel<false><<<ablocks, tb, 0, stream>>>(Hb, offs, csr, dinv, nullptr,
                                                           nullptr, nullptr, 0.0f, Ab, n);
    bn_stats_kernel<<<256, tb, 0, stream>>>(Ab, stats, n);
    // layer 2: BN1+ReLU fused into gemm A-staging
    gemm128_mfma_kernel<1><<<gblocks, tb, 0, stream>>>(Ab, WT2, stats, g1, bt1, invn, Hb, n);
    aggregate128_kernel<false><<<ablocks, tb, 0, stream>>>(Hb, offs, csr, dinv, nullptr,
                                                           nullptr, nullptr, 0.0f, Ab2, n);
    bn_stats_kernel<<<256, tb, 0, stream>>>(Ab2, stats + 256, n);
    // layer 3: BN2+ReLU fused into aggregation gather; then GEMM + fused log_softmax
    aggregate128_kernel<true><<<ablocks, tb, 0, stream>>>(Ab2, offs, csr, dinv, stats + 256,
                                                          g2, bt2, invn, Hb2, n);
    gemm40_lsm_mfma_kernel<<<gblocks, tb, 0, stream>>>(Hb2, WT3, b3, (float*)d_out, n);
}